// Round 5
// baseline (163.566 us; speedup 1.0000x reference)
//
#include <hip/hip_runtime.h>
#include <math.h>

#define NUM_TASKS 16
#define B_ROWS    8192
#define BM        128
#define BK        64
#define MAX_TILES (B_ROWS / BM + NUM_TASKS)   // 80

typedef __attribute__((ext_vector_type(4))) float f32x4;
typedef __attribute__((ext_vector_type(8))) short bf16x8;
typedef __attribute__((ext_vector_type(4))) short bf16x4;
typedef unsigned short ushort_t;

__device__ __forceinline__ short f2bf(float f) {
    union { float f; unsigned u; } c; c.f = f;
    unsigned u = c.u;
    unsigned r = (u + 0x7FFFu + ((u >> 16) & 1u)) >> 16;
    return (short)r;
}

__device__ __forceinline__ void gld16(const void* g, void* l) {
    __builtin_amdgcn_global_load_lds(
        (const __attribute__((address_space(1))) unsigned int*)g,
        (__attribute__((address_space(3))) unsigned int*)l,
        16, 0, 0);
}

// ---------------------------------------------------------------------------
// Bucket kernel: deterministic (stable) counting sort of rows by task.
// ---------------------------------------------------------------------------
__global__ __launch_bounds__(256) void bucket_kernel(
    const int* __restrict__ task_ids,
    int* __restrict__ sidx,
    int* __restrict__ tile_base,
    int* __restrict__ tile_task,
    int* __restrict__ tile_end,
    int* __restrict__ ntiles)
{
    __shared__ int cnt[256][NUM_TASKS];
    __shared__ int offs[NUM_TASKS + 1];
    __shared__ int tot[NUM_TASKS];

    const int tid = threadIdx.x;
    #pragma unroll
    for (int t = 0; t < NUM_TASKS; ++t) cnt[tid][t] = 0;
    const int base = tid * (B_ROWS / 256);

    for (int i = 0; i < B_ROWS / 256; ++i) {
        int t = task_ids[base + i];
        cnt[tid][t]++;
    }
    __syncthreads();

    if (tid < NUM_TASKS) {
        int s = 0;
        for (int c = 0; c < 256; ++c) { int v = cnt[c][tid]; cnt[c][tid] = s; s += v; }
        tot[tid] = s;
    }
    __syncthreads();

    if (tid == 0) {
        int s = 0;
        for (int t = 0; t < NUM_TASKS; ++t) { offs[t] = s; s += tot[t]; }
        offs[NUM_TASKS] = s;
        int nt = 0;
        for (int t = 0; t < NUM_TASKS; ++t) {
            for (int r = offs[t]; r < offs[t + 1]; r += BM) {
                tile_base[nt] = r;
                tile_task[nt] = t;
                tile_end[nt]  = offs[t + 1];
                nt++;
            }
        }
        *ntiles = nt;
    }
    __syncthreads();

    for (int i = 0; i < B_ROWS / 256; ++i) {
        int row = base + i;
        int t = task_ids[row];
        int pos = offs[t] + cnt[tid][t];
        cnt[tid][t] = cnt[tid][t] + 1;
        sidx[pos] = row;
    }
}

// ---------------------------------------------------------------------------
// x gather+convert: xs[pos][c] = bf16(x[sidx[pos]][c]); 4 rows per block.
// ---------------------------------------------------------------------------
__global__ __launch_bounds__(256) void xconv(
    const float* __restrict__ x,
    const int* __restrict__ sidx,
    ushort_t* __restrict__ xs)
{
    const int tid  = threadIdx.x;
    const int lrow = tid >> 6;
    const int lane = tid & 63;
    const int pos  = blockIdx.x * 4 + lrow;
    const int src  = sidx[pos];
    const float* sp = x + (size_t)src * 512 + lane * 8;
    f32x4 v0 = *(const f32x4*)sp;
    f32x4 v1 = *(const f32x4*)(sp + 4);
    bf16x8 pk;
    pk[0] = f2bf(v0[0]); pk[1] = f2bf(v0[1]);
    pk[2] = f2bf(v0[2]); pk[3] = f2bf(v0[3]);
    pk[4] = f2bf(v1[0]); pk[5] = f2bf(v1[1]);
    pk[6] = f2bf(v1[2]); pk[7] = f2bf(v1[3]);
    *(bf16x8*)(xs + (size_t)pos * 512 + lane * 8) = pk;
}

// ---------------------------------------------------------------------------
// Weight convert + transpose: W[t][k][n] fp32 -> Wt[t][n][k] bf16.
// ---------------------------------------------------------------------------
template<int K, int N>
__global__ __launch_bounds__(256) void wconv(
    const float* __restrict__ W, ushort_t* __restrict__ Wt)
{
    const int t  = blockIdx.z;
    const int kb = blockIdx.y * 64;
    const int nb = blockIdx.x * 64;
    const float* src = W + (size_t)t * K * N;
    ushort_t* dst = Wt + (size_t)t * N * K;

    __shared__ ushort_t tile[64][68];

    const int tid = threadIdx.x;
    {
        int kl  = tid >> 4;
        int nl4 = (tid & 15) * 4;
        #pragma unroll
        for (int r = 0; r < 4; ++r) {
            int k = kl + r * 16;
            f32x4 v = *(const f32x4*)(src + (size_t)(kb + k) * N + nb + nl4);
            tile[nl4 + 0][k] = (ushort_t)f2bf(v[0]);
            tile[nl4 + 1][k] = (ushort_t)f2bf(v[1]);
            tile[nl4 + 2][k] = (ushort_t)f2bf(v[2]);
            tile[nl4 + 3][k] = (ushort_t)f2bf(v[3]);
        }
    }
    __syncthreads();
    {
        int nl = tid >> 2;
        int c  = (tid & 3) * 16;
        bf16x4 v0 = *(const bf16x4*)&tile[nl][c + 0];
        bf16x4 v1 = *(const bf16x4*)&tile[nl][c + 4];
        bf16x4 v2 = *(const bf16x4*)&tile[nl][c + 8];
        bf16x4 v3 = *(const bf16x4*)&tile[nl][c + 12];
        ushort_t* dp = dst + (size_t)(nb + nl) * K + kb + c;
        *(bf16x4*)(dp + 0)  = v0;
        *(bf16x4*)(dp + 4)  = v1;
        *(bf16x4*)(dp + 8)  = v2;
        *(bf16x4*)(dp + 12) = v3;
    }
}

// ---------------------------------------------------------------------------
// Grouped GEMM layer: 512 threads = 8 waves (2 x 4), BM=128 x BN_ (128/64),
// BK=64. Quad-buffered LDS, prefetch depth 3, counted vmcnt (never 0 in
// steady state), builtin s_barrier (m201 pattern), setprio around MFMAs.
// In-flight per CU: 8 waves x 3 batches x LPB loads x 1KB ~= 96 KB.
// ---------------------------------------------------------------------------
template<int K, int N, int BN_, int OUT_FINAL>
__global__ __launch_bounds__(512, 2) void mlp_gemm(
    const ushort_t* __restrict__ in,
    const ushort_t* __restrict__ wt,      // [T][N][K] bf16
    const float* __restrict__ bias,
    void* __restrict__ out,
    const int* __restrict__ sidx,
    const int* __restrict__ tile_base,
    const int* __restrict__ tile_task,
    const int* __restrict__ tile_end,
    const int* __restrict__ ntiles)
{
    constexpr int NBLKN = N / BN_;
    constexpr int NB    = NBLKN * MAX_TILES;
    constexpr int NT    = K / BK;
    constexpr int AR    = (BM * BK) / 4096;    // 2 rounds for A
    constexpr int BR    = (BN_ * BK) / 4096;   // 2 (BN=128) or 1 (BN=64)
    constexpr int LPB   = AR + BR;             // loads per batch per wave
    constexpr int NF    = BN_ / 64;            // 2 or 1
    constexpr int WNW   = BN_ / 4;             // per-wave N width
    constexpr int LDSE  = (BM + BN_) * BK;     // elems per buffer

    // bijective XCD swizzle (m204)
    const int orig = blockIdx.x;
    constexpr int q = NB / 8, rr = NB % 8;
    const int xcd = orig & 7, idx = orig >> 3;
    const int wgid = (xcd < rr ? xcd * (q + 1) : rr * (q + 1) + (xcd - rr) * q) + idx;
    const int tile = wgid / NBLKN;
    const int n0   = (wgid % NBLKN) * BN_;

    if (tile >= *ntiles) return;
    const int rowbase = tile_base[tile];
    const int task    = tile_task[tile];
    const int rowend  = tile_end[tile];

    __shared__ __align__(16) short LDSb[4][LDSE];   // 128 KB (BN=128) / 96 KB

    const int tid  = threadIdx.x;
    const int lane = tid & 63;
    const int wid  = tid >> 6;        // 0..7
    const int wm   = wid >> 2;        // 0..1 : 64-row half
    const int wn   = wid & 3;         // 0..3 : WNW-col slice

    f32x4 acc[4][NF];
    #pragma unroll
    for (int mf = 0; mf < 4; ++mf)
        #pragma unroll
        for (int nf = 0; nf < NF; ++nf)
            acc[mf][nf] = (f32x4){0.f, 0.f, 0.f, 0.f};

    // staging geometry: round = 4096 elems (512 thr x 8); 64 rows per round.
    // pre-swizzled global source, linear LDS dest.
    const int srow = wid * 8 + (lane >> 3);   // 0..63 row within round
    const int spos = lane & 7;                // chunk slot in LDS row
    const int kc0  = spos ^ (srow & 7);       // k-chunk for that slot

    const ushort_t* Wtt = wt + (size_t)task * N * K;

    const ushort_t* aglob[AR];
    const ushort_t* bglob[BR];
    #pragma unroll
    for (int r = 0; r < AR; ++r) {
        int ga = rowbase + r * 64 + srow;
        if (ga > B_ROWS - 1) ga = B_ROWS - 1;
        aglob[r] = in + (size_t)ga * K + kc0 * 8;
    }
    #pragma unroll
    for (int r = 0; r < BR; ++r)
        bglob[r] = Wtt + (size_t)(n0 + r * 64 + srow) * K + kc0 * 8;

    const int r16 = lane & 15;
    const int khi = lane >> 4;

#define STAGE(BI, TI)                                                        \
    {                                                                        \
        short* Ab_ = &LDSb[(BI)][0] + wid * 512;                             \
        short* Bb_ = &LDSb[(BI)][BM * BK] + wid * 512;                       \
        const size_t ke_ = (size_t)(TI) * BK;                                \
        _Pragma("unroll")                                                    \
        for (int r_ = 0; r_ < AR; ++r_) gld16(aglob[r_] + ke_, Ab_ + r_ * 4096); \
        _Pragma("unroll")                                                    \
        for (int r_ = 0; r_ < BR; ++r_) gld16(bglob[r_] + ke_, Bb_ + r_ * 4096); \
    }

    // prologue: stage batches 0,1,2 (NT >= 8 always)
    STAGE(0, 0)
    STAGE(1, 1)
    STAGE(2, 2)

    #pragma unroll
    for (int t = 0; t < NT; ++t) {
        if (t + 3 < NT) {
            STAGE((t + 3) & 3, t + 3)
            asm volatile("s_waitcnt vmcnt(%0)" :: "n"(3 * LPB) : "memory");
        } else if (t + 3 == NT) {
            asm volatile("s_waitcnt vmcnt(%0)" :: "n"(2 * LPB) : "memory");
        } else if (t + 2 == NT) {
            asm volatile("s_waitcnt vmcnt(%0)" :: "n"(1 * LPB) : "memory");
        } else {
            asm volatile("s_waitcnt vmcnt(0)" ::: "memory");
        }
        __builtin_amdgcn_s_barrier();

        const short* Abase = &LDSb[t & 3][0];
        const short* Bbase = &LDSb[t & 3][BM * BK];
        #pragma unroll
        for (int ks = 0; ks < 2; ++ks) {
            bf16x8 a[4], b[NF];
            const int kc = ks * 4 + khi;
            #pragma unroll
            for (int mf = 0; mf < 4; ++mf) {
                int row = wm * 64 + mf * 16 + r16;
                a[mf] = *(const bf16x8*)&Abase[row * 64 + (kc ^ (row & 7)) * 8];
            }
            #pragma unroll
            for (int nf = 0; nf < NF; ++nf) {
                int col = wn * WNW + nf * 16 + r16;
                b[nf] = *(const bf16x8*)&Bbase[col * 64 + (kc ^ (col & 7)) * 8];
            }
            __builtin_amdgcn_s_setprio(1);
            #pragma unroll
            for (int mf = 0; mf < 4; ++mf)
                #pragma unroll
                for (int nf = 0; nf < NF; ++nf)
                    acc[mf][nf] = __builtin_amdgcn_mfma_f32_16x16x32_bf16(
                        a[mf], b[nf], acc[mf][nf], 0, 0, 0);
            __builtin_amdgcn_s_setprio(0);
        }
        __builtin_amdgcn_s_barrier();
    }
#undef STAGE

    // ---- epilogue ----
    {
        const int rg = lane >> 4;
        #pragma unroll
        for (int nf = 0; nf < NF; ++nf) {
            const int col = n0 + wn * WNW + nf * 16 + r16;
            const float bv = bias[(size_t)task * N + col];
            #pragma unroll
            for (int mf = 0; mf < 4; ++mf) {
                #pragma unroll
                for (int r = 0; r < 4; ++r) {
                    int row_l = wm * 64 + mf * 16 + rg * 4 + r;
                    int grow = rowbase + row_l;
                    if (grow < rowend) {
                        float v = acc[mf][nf][r] + bv;
                        if (!OUT_FINAL) {
                            v = tanhf(v);
                            ((ushort_t*)out)[(size_t)grow * N + col] =
                                (ushort_t)f2bf(v);
                        } else {
                            ((float*)out)[(size_t)sidx[grow] * N + col] = v;
                        }
                    }
                }
            }
        }
    }
}

// ---------------------------------------------------------------------------
extern "C" void kernel_launch(void* const* d_in, const int* in_sizes, int n_in,
                              void* d_out, int out_size, void* d_ws, size_t ws_size,
                              hipStream_t stream)
{
    const float* x        = (const float*)d_in[0];
    const int*   task_ids = (const int*)  d_in[1];
    const float* k0       = (const float*)d_in[2];
    const float* b0       = (const float*)d_in[3];
    const float* k1       = (const float*)d_in[4];
    const float* b1       = (const float*)d_in[5];
    const float* k2       = (const float*)d_in[6];
    const float* b2       = (const float*)d_in[7];
    float* out = (float*)d_out;

    char* ws = (char*)d_ws;
    int* sidx      = (int*)ws;
    int* tile_base = sidx + 8192;
    int* tile_task = tile_base + 128;
    int* tile_end  = tile_task + 128;
    int* ntiles    = tile_end + 128;

    size_t off = 65536;
    ushort_t* xs  = (ushort_t*)(ws + off); off += (size_t)8192 * 512 * 2;
    ushort_t* H0  = (ushort_t*)(ws + off); off += (size_t)8192 * 1024 * 2;
    ushort_t* H1  = (ushort_t*)(ws + off); off += (size_t)8192 * 1024 * 2;
    ushort_t* Wt0 = (ushort_t*)(ws + off); off += (size_t)16 * 512 * 1024 * 2;
    ushort_t* Wt1 = (ushort_t*)(ws + off); off += (size_t)16 * 1024 * 1024 * 2;
    ushort_t* Wt2 = (ushort_t*)(ws + off); off += (size_t)16 * 1024 * 256 * 2;

    bucket_kernel<<<1, 256, 0, stream>>>(task_ids, sidx, tile_base, tile_task,
                                         tile_end, ntiles);
    xconv<<<2048, 256, 0, stream>>>(x, sidx, xs);
    wconv< 512, 1024><<<dim3(16,  8, 16), 256, 0, stream>>>(k0, Wt0);
    wconv<1024, 1024><<<dim3(16, 16, 16), 256, 0, stream>>>(k1, Wt1);
    wconv<1024,  256><<<dim3( 4, 16, 16), 256, 0, stream>>>(k2, Wt2);

    mlp_gemm< 512, 1024, 128, 0><<<8 * MAX_TILES, 512, 0, stream>>>(
        xs, Wt0, b0, H0, sidx, tile_base, tile_task, tile_end, ntiles);
    mlp_gemm<1024, 1024, 128, 0><<<8 * MAX_TILES, 512, 0, stream>>>(
        H0, Wt1, b1, H1, sidx, tile_base, tile_task, tile_end, ntiles);
    mlp_gemm<1024,  256,  64, 1><<<4 * MAX_TILES, 512, 0, stream>>>(
        H1, Wt2, b2, out, sidx, tile_base, tile_task, tile_end, ntiles);
}